// Round 12
// baseline (474.649 us; speedup 1.0000x reference)
//
#include <hip/hip_runtime.h>
#include <hip/hip_bf16.h>

// Trittention, factorized:
//   z[q,h] = sum_{t<=q} Eqk[q,t]*v2[t,h]*G_q[t,h] / sum_{t<=q} Eqk[q,t]*g_q[t]
//   G_q[t,h] = sum_{s<=q} Ekk[s,t]*silu(v1)[s,h]   (prefix over s)
// R11: persistent mega-kernel, coop-launched at 1024 blocks (4/CU), custom
// grid barrier with BLOCK-LEADER fences (1 threadfence per block, not per
// thread; __syncthreads drains stores first) + low-rate s_sleep(16) spin.
// R9/R10 showed ~85us/barrier regardless of barrier algorithm -> cost is
// per-wave L2 wb/inv + spin contention; this cuts both ~256x/~30x.
// Cascade: coop 1024 -> coop 512 -> R7-style 4-kernel fallback.

constexpr int Tn = 192;
constexpr int DM = 512;
constexpr int NH = 8;
constexpr int HD = 64;
constexpr int TT = Tn * Tn;
constexpr int NCc = 6;           // chunks of 32 s-rows
constexpr int CSc = 32;

typedef __bf16 bf16_t;
typedef bf16_t bf16x8 __attribute__((ext_vector_type(8)));
typedef float  f32x4  __attribute__((ext_vector_type(4)));

struct bf16pair { bf16_t h, l; };
__device__ __forceinline__ bf16pair split_bf16(float v) {
    bf16pair r;
    r.h = (bf16_t)v;
    r.l = (bf16_t)(v - (float)r.h);
    return r;
}

// Grid barrier, monotonic counter (pre-zeroed by hipMemsetAsync each launch).
// __syncthreads() drains every wave's stores to L2 (compiler emits
// s_waitcnt vmcnt(0) before s_barrier); one leader thread then does the
// agent-scope fence (L2 writeback) + counter add + spin + acquire fence
// (L1/L2 invalidate). Every CU hosts >=1 block leader -> all caches maintained.
__device__ __forceinline__ void grid_barrier(unsigned* cnt, unsigned target, int tid) {
    __syncthreads();
    if (tid == 0) {
        __threadfence();   // release: wb this XCD's L2 (block's stores already in L2)
        __hip_atomic_fetch_add(cnt, 1u, __ATOMIC_RELAXED, __HIP_MEMORY_SCOPE_AGENT);
        while (__hip_atomic_load(cnt, __ATOMIC_RELAXED, __HIP_MEMORY_SCOPE_AGENT) < target) {
            __builtin_amdgcn_s_sleep(16);   // ~1us poll: low coherence-point contention
        }
        __threadfence();   // acquire: invalidate L1/L2 before post-barrier reads
    }
    __syncthreads();
}

// ================= Phase 1: projection GEMM =================
__device__ __forceinline__ void phase1(
    const float* __restrict__ x,
    const float* __restrict__ Wkkq, const float* __restrict__ Wv1,
    const float* __restrict__ Wv2,
    const float* __restrict__ bkkq, const float* __restrict__ bv1,
    const float* __restrict__ bv2,
    float* __restrict__ k1, float* __restrict__ k2, float* __restrict__ qv,
    float* __restrict__ sv1, float* __restrict__ v2o,
    int bid0, int nblk, int tid)
{
    const int w = tid >> 6, lane = tid & 63;
    const int wm = w & 1, wn = w >> 1;
    const int lr = lane & 15, lk = (lane >> 4) * 8;

    for (int wi = bid0; wi < 960; wi += nblk) {
        const int bx = wi % 80, by = wi / 80;

        const float* Wp; int ldw, cloc;
        if (bx < 48)      { Wp = Wkkq; ldw = 1536; cloc = bx * 32; }
        else if (bx < 64) { Wp = Wv1;  ldw = 512;  cloc = bx * 32 - 1536; }
        else              { Wp = Wv2;  ldw = 512;  cloc = bx * 32 - 2048; }

        const int arow = by * 32 + wm * 16 + lr;
        const int bcol = cloc + wn * 16 + lr;
        const float* xrow = x + arow * DM;

        f32x4 acc = {0.f,0.f,0.f,0.f};
        bf16x8 A_ah, A_al, A_bh, A_bl;
        bf16x8 B_ah, B_al, B_bh, B_bl;

#define PLD(P_, KS) do { const int ko_ = (KS) * 32 + lk;                                  \
    const float4 u0 = *reinterpret_cast<const float4*>(&xrow[ko_]);                       \
    const float4 u1 = *reinterpret_cast<const float4*>(&xrow[ko_ + 4]);                   \
    const float* wp_ = Wp + ko_ * ldw + bcol;                                             \
    const float w0_ = wp_[0],       w1_ = wp_[ldw],     w2_ = wp_[2 * ldw];               \
    const float w3_ = wp_[3 * ldw], w4_ = wp_[4 * ldw], w5_ = wp_[5 * ldw];               \
    const float w6_ = wp_[6 * ldw], w7_ = wp_[7 * ldw];                                   \
    bf16pair t0_ = split_bf16(u0.x), t1_ = split_bf16(u0.y);                              \
    bf16pair t2_ = split_bf16(u0.z), t3_ = split_bf16(u0.w);                              \
    bf16pair t4_ = split_bf16(u1.x), t5_ = split_bf16(u1.y);                              \
    bf16pair t6_ = split_bf16(u1.z), t7_ = split_bf16(u1.w);                              \
    P_##ah[0] = t0_.h; P_##al[0] = t0_.l; P_##ah[1] = t1_.h; P_##al[1] = t1_.l;           \
    P_##ah[2] = t2_.h; P_##al[2] = t2_.l; P_##ah[3] = t3_.h; P_##al[3] = t3_.l;           \
    P_##ah[4] = t4_.h; P_##al[4] = t4_.l; P_##ah[5] = t5_.h; P_##al[5] = t5_.l;           \
    P_##ah[6] = t6_.h; P_##al[6] = t6_.l; P_##ah[7] = t7_.h; P_##al[7] = t7_.l;           \
    bf16pair s0_ = split_bf16(w0_), s1_ = split_bf16(w1_);                                \
    bf16pair s2_ = split_bf16(w2_), s3_ = split_bf16(w3_);                                \
    bf16pair s4_ = split_bf16(w4_), s5_ = split_bf16(w5_);                                \
    bf16pair s6_ = split_bf16(w6_), s7_ = split_bf16(w7_);                                \
    P_##bh[0] = s0_.h; P_##bl[0] = s0_.l; P_##bh[1] = s1_.h; P_##bl[1] = s1_.l;           \
    P_##bh[2] = s2_.h; P_##bl[2] = s2_.l; P_##bh[3] = s3_.h; P_##bl[3] = s3_.l;           \
    P_##bh[4] = s4_.h; P_##bl[4] = s4_.l; P_##bh[5] = s5_.h; P_##bl[5] = s5_.l;           \
    P_##bh[6] = s6_.h; P_##bl[6] = s6_.l; P_##bh[7] = s7_.h; P_##bl[7] = s7_.l; } while (0)
#define PMM(P_) do {                                                                    \
    acc = __builtin_amdgcn_mfma_f32_16x16x32_bf16(P_##ah, P_##bh, acc, 0, 0, 0);        \
    acc = __builtin_amdgcn_mfma_f32_16x16x32_bf16(P_##ah, P_##bl, acc, 0, 0, 0);        \
    acc = __builtin_amdgcn_mfma_f32_16x16x32_bf16(P_##al, P_##bh, acc, 0, 0, 0); } while (0)
#define PSTEP(P_, KN) do { PMM(P_); if ((KN) < 16) PLD(P_, KN); } while (0)

        PLD(A_, 0); PLD(B_, 1);
        PSTEP(A_, 2);  PSTEP(B_, 3);  PSTEP(A_, 4);  PSTEP(B_, 5);
        PSTEP(A_, 6);  PSTEP(B_, 7);  PSTEP(A_, 8);  PSTEP(B_, 9);
        PSTEP(A_, 10); PSTEP(B_, 11); PSTEP(A_, 12); PSTEP(B_, 13);
        PSTEP(A_, 14); PSTEP(B_, 15); PSTEP(A_, 16); PSTEP(B_, 17);
#undef PLD
#undef PMM
#undef PSTEP

        const int gcol = bx * 32 + wn * 16 + lr;
#pragma unroll
        for (int r = 0; r < 4; ++r) {
            const int row = by * 32 + wm * 16 + (lane >> 4) * 4 + r;
            const int b = row / Tn, t = row % Tn;
            const float a = acc[r];
            if (gcol < 1536) {
                const float val = a + bkkq[gcol];
                const int third = gcol >> 9, nh = gcol & 511, n = nh >> 6, hh = nh & 63;
                float* dst = (third == 0) ? k1 : (third == 1) ? k2 : qv;
                dst[((b * NH + n) * Tn + t) * HD + hh] = val;
            } else if (gcol < 2048) {
                const int c = gcol - 1536;
                float val = a + bv1[c];
                val = val / (1.f + __expf(-val));
                sv1[((b * NH + (c >> 6)) * Tn + t) * HD + (c & 63)] = val;
            } else {
                const int c = gcol - 2048;
                v2o[((b * NH + (c >> 6)) * Tn + t) * HD + (c & 63)] = a + bv2[c];
            }
        }
    }
}

// ================= Phase 2: exp tables + chunk partials =================
__device__ __forceinline__ void phase2(
    const float* __restrict__ k1, const float* __restrict__ k2,
    const float* __restrict__ qv, const float* __restrict__ sv1,
    float* __restrict__ Ekk, float* __restrict__ Eqk,
    float* __restrict__ P, float* __restrict__ gP,
    int bid0, int nblk, int tid)
{
    __shared__ float As[32][65], Bs[32][65], Vs[32][65];
    __shared__ float Es[32][33];

    for (int wi = bid0; wi < 1152; wi += nblk) {
        const int bn = wi / 72;
        int bx = wi % 72;
        const int mat = (bx >= 36) ? 1 : 0;
        if (mat) bx -= 36;
        const int st = bx / 6, tt = bx % 6;
        const float* A  = ((mat == 0) ? k1 : qv) + bn * Tn * HD;
        const float* Bm = k2 + bn * Tn * HD;
        float* E = ((mat == 0) ? Ekk : Eqk) + bn * TT;

        for (int i = tid; i < 32 * 64; i += 256) {
            const int r = i >> 6, h = i & 63;
            As[r][h] = A[(st * 32 + r) * HD + h];
            Bs[r][h] = Bm[(tt * 32 + r) * HD + h];
            if (mat == 0) Vs[r][h] = sv1[bn * Tn * HD + (st * 32 + r) * HD + h];
        }
        __syncthreads();

        const int tx = tid & 15, ty = tid >> 4;
        const int r0 = ty * 2, c0 = tx * 2;
        float a00 = 0.f, a01 = 0.f, a10 = 0.f, a11 = 0.f;
#pragma unroll
        for (int h = 0; h < 64; ++h) {
            const float ar0 = As[r0][h], ar1 = As[r0 + 1][h];
            const float bc0 = Bs[c0][h], bc1 = Bs[c0 + 1][h];
            a00 = fmaf(ar0, bc0, a00); a01 = fmaf(ar0, bc1, a01);
            a10 = fmaf(ar1, bc0, a10); a11 = fmaf(ar1, bc1, a11);
        }
        constexpr float sc = 1.f / 64.f;
        const float e00 = __expf(a00 * sc), e01 = __expf(a01 * sc);
        const float e10 = __expf(a10 * sc), e11 = __expf(a11 * sc);
        const int gr = st * 32 + r0, gc = tt * 32 + c0;
        E[(gr)     * Tn + gc]     = e00;
        E[(gr)     * Tn + gc + 1] = e01;
        E[(gr + 1) * Tn + gc]     = e10;
        E[(gr + 1) * Tn + gc + 1] = e11;

        if (mat == 0) {
            Es[r0][c0] = e00; Es[r0][c0 + 1] = e01;
            Es[r0 + 1][c0] = e10; Es[r0 + 1][c0 + 1] = e11;
            __syncthreads();

            const int h   = tid >> 2;
            const int tp0 = (tid & 3) * 8;
            float p[8] = {0.f,0.f,0.f,0.f,0.f,0.f,0.f,0.f};
            for (int s = 0; s < 32; ++s) {
                const float a = Vs[s][h];
#pragma unroll
                for (int j = 0; j < 8; ++j) p[j] = fmaf(Es[s][tp0 + j], a, p[j]);
            }
            float* pd = P + ((bn * NCc + st) * HD + h) * Tn + tt * 32 + tp0;
            *reinterpret_cast<float4*>(&pd[0]) = make_float4(p[0], p[1], p[2], p[3]);
            *reinterpret_cast<float4*>(&pd[4]) = make_float4(p[4], p[5], p[6], p[7]);

            if (tid < 32) {
                float s = 0.f;
#pragma unroll
                for (int ss = 0; ss < 32; ++ss) s += Es[ss][tid];
                gP[(bn * NCc + st) * Tn + tt * 32 + tid] = s;
            }
        }
        __syncthreads();   // protect As/Bs/Vs/Es before next grid-stride iter
    }
}

// ================= Phase 3: attention from chunk partials =================
__device__ __forceinline__ void phase3(
    const float* __restrict__ Ekk, const float* __restrict__ Eqk,
    const float* __restrict__ sv1, const float* __restrict__ v2o,
    const float* __restrict__ P,   const float* __restrict__ gP,
    float* __restrict__ z,
    int bid0, int nblk, int tid)
{
    const int tg = tid & 15, hh = tid >> 4;
    for (int wi = bid0; wi < 1024; wi += nblk) {
        const int hq = wi & 3;
        const int qt = (wi >> 2) & 15;
        const int bn = wi >> 6;
        const int b = bn >> 3, n = bn & 7;
        const int h  = hq * 16 + hh;
        const int t0 = tg * 12;
        const int q0 = qt * 12;
        const int cb = q0 >> 5;

        const float* ekk = Ekk + bn * TT;
        const float* eqk = Eqk + bn * TT;
        const float* s1  = sv1 + bn * Tn * HD;
        const float* vv  = v2o + bn * Tn * HD;

        float G[12], g[12];
#pragma unroll
        for (int j = 0; j < 12; ++j) { G[j] = 0.f; g[j] = 0.f; }

        for (int c = 0; c < cb; ++c) {
            const float* pb = P  + ((bn * NCc + c) * HD + h) * Tn + t0;
            const float* gb = gP + (bn * NCc + c) * Tn + t0;
#pragma unroll
            for (int jj = 0; jj < 3; ++jj) {
                const float4 pv = *reinterpret_cast<const float4*>(&pb[4 * jj]);
                G[4*jj+0] += pv.x; G[4*jj+1] += pv.y; G[4*jj+2] += pv.z; G[4*jj+3] += pv.w;
                const float4 gv = *reinterpret_cast<const float4*>(&gb[4 * jj]);
                g[4*jj+0] += gv.x; g[4*jj+1] += gv.y; g[4*jj+2] += gv.z; g[4*jj+3] += gv.w;
            }
        }

        float vvr[12];
#pragma unroll
        for (int j = 0; j < 12; ++j) vvr[j] = vv[(t0 + j) * HD + h];

        for (int s = CSc * cb; s < q0; ++s) {
            const float a = s1[s * HD + h];
            const float* ek = ekk + s * Tn + t0;
#pragma unroll
            for (int jj = 0; jj < 3; ++jj) {
                const float4 ev = *reinterpret_cast<const float4*>(&ek[4 * jj]);
                G[4*jj+0] = fmaf(ev.x, a, G[4*jj+0]); g[4*jj+0] += ev.x;
                G[4*jj+1] = fmaf(ev.y, a, G[4*jj+1]); g[4*jj+1] += ev.y;
                G[4*jj+2] = fmaf(ev.z, a, G[4*jj+2]); g[4*jj+2] += ev.z;
                G[4*jj+3] = fmaf(ev.w, a, G[4*jj+3]); g[4*jj+3] += ev.w;
            }
        }

        for (int q = q0; q < q0 + 12; ++q) {
            {
                const float a = s1[q * HD + h];
                const float* ek = ekk + q * Tn + t0;
#pragma unroll
                for (int jj = 0; jj < 3; ++jj) {
                    const float4 ev = *reinterpret_cast<const float4*>(&ek[4 * jj]);
                    G[4*jj+0] = fmaf(ev.x, a, G[4*jj+0]); g[4*jj+0] += ev.x;
                    G[4*jj+1] = fmaf(ev.y, a, G[4*jj+1]); g[4*jj+1] += ev.y;
                    G[4*jj+2] = fmaf(ev.z, a, G[4*jj+2]); g[4*jj+2] += ev.z;
                    G[4*jj+3] = fmaf(ev.w, a, G[4*jj+3]); g[4*jj+3] += ev.w;
                }
            }
            const float* eq = eqk + q * Tn + t0;
            float zp = 0.f, Zp = 0.f;
#pragma unroll
            for (int jj = 0; jj < 3; ++jj) {
                const float4 ev = *reinterpret_cast<const float4*>(&eq[4 * jj]);
                const float e0 = (t0 + 4*jj + 0 <= q) ? ev.x : 0.f;
                const float e1 = (t0 + 4*jj + 1 <= q) ? ev.y : 0.f;
                const float e2 = (t0 + 4*jj + 2 <= q) ? ev.z : 0.f;
                const float e3 = (t0 + 4*jj + 3 <= q) ? ev.w : 0.f;
                zp = fmaf(e0 * vvr[4*jj+0], G[4*jj+0], zp); Zp = fmaf(e0, g[4*jj+0], Zp);
                zp = fmaf(e1 * vvr[4*jj+1], G[4*jj+1], zp); Zp = fmaf(e1, g[4*jj+1], Zp);
                zp = fmaf(e2 * vvr[4*jj+2], G[4*jj+2], zp); Zp = fmaf(e2, g[4*jj+2], Zp);
                zp = fmaf(e3 * vvr[4*jj+3], G[4*jj+3], zp); Zp = fmaf(e3, g[4*jj+3], Zp);
            }
            zp += __shfl_xor(zp, 1); zp += __shfl_xor(zp, 2);
            zp += __shfl_xor(zp, 4); zp += __shfl_xor(zp, 8);
            Zp += __shfl_xor(Zp, 1); Zp += __shfl_xor(Zp, 2);
            Zp += __shfl_xor(Zp, 4); Zp += __shfl_xor(Zp, 8);
            if (tg == 0) z[((b * Tn + q) * NH + n) * HD + h] = zp / Zp;
        }
    }
}

// ================= Phase 4: output projection =================
__device__ __forceinline__ void phase4(
    const float* __restrict__ z, const float* __restrict__ Wout,
    const float* __restrict__ bout, float* __restrict__ out,
    int bid0, int nblk, int tid)
{
    const int w = tid >> 6, lane = tid & 63;
    const int lr = lane & 15, lk = (lane >> 4) * 8;
    for (int wi = bid0; wi < 192; wi += nblk) {
        const int bx = wi % 8, by = wi / 8;
        const int arow = by * 16 + lr;
        const int bcol = bx * 64 + w * 16 + lr;
        const float* zrow = z + arow * DM;

        f32x4 acc = {0.f,0.f,0.f,0.f};
        bf16x8 A_ah, A_al, A_bh, A_bl;
        bf16x8 B_ah, B_al, B_bh, B_bl;

#define OLD(P_, KS) do { const int ko_ = (KS) * 32 + lk;                                  \
    const float4 u0 = *reinterpret_cast<const float4*>(&zrow[ko_]);                       \
    const float4 u1 = *reinterpret_cast<const float4*>(&zrow[ko_ + 4]);                   \
    const float* wp_ = Wout + ko_ * DM + bcol;                                            \
    const float w0_ = wp_[0],      w1_ = wp_[DM],     w2_ = wp_[2 * DM];                  \
    const float w3_ = wp_[3 * DM], w4_ = wp_[4 * DM], w5_ = wp_[5 * DM];                  \
    const float w6_ = wp_[6 * DM], w7_ = wp_[7 * DM];                                     \
    bf16pair t0_ = split_bf16(u0.x), t1_ = split_bf16(u0.y);                              \
    bf16pair t2_ = split_bf16(u0.z), t3_ = split_bf16(u0.w);                              \
    bf16pair t4_ = split_bf16(u1.x), t5_ = split_bf16(u1.y);                              \
    bf16pair t6_ = split_bf16(u1.z), t7_ = split_bf16(u1.w);                              \
    P_##ah[0] = t0_.h; P_##al[0] = t0_.l; P_##ah[1] = t1_.h; P_##al[1] = t1_.l;           \
    P_##ah[2] = t2_.h; P_##al[2] = t2_.l; P_##ah[3] = t3_.h; P_##al[3] = t3_.l;           \
    P_##ah[4] = t4_.h; P_##al[4] = t4_.l; P_##ah[5] = t5_.h; P_##al[5] = t5_.l;           \
    P_##ah[6] = t6_.h; P_##al[6] = t6_.l; P_##ah[7] = t7_.h; P_##al[7] = t7_.l;           \
    bf16pair s0_ = split_bf16(w0_), s1_ = split_bf16(w1_);                                \
    bf16pair s2_ = split_bf16(w2_), s3_ = split_bf16(w3_);                                \
    bf16pair s4_ = split_bf16(w4_), s5_ = split_bf16(w5_);                                \
    bf16pair s6_ = split_bf16(w6_), s7_ = split_bf16(w7_);                                \
    P_##bh[0] = s0_.h; P_##bl[0] = s0_.l; P_##bh[1] = s1_.h; P_##bl[1] = s1_.l;           \
    P_##bh[2] = s2_.h; P_##bl[2] = s2_.l; P_##bh[3] = s3_.h; P_##bl[3] = s3_.l;           \
    P_##bh[4] = s4_.h; P_##bl[4] = s4_.l; P_##bh[5] = s5_.h; P_##bl[5] = s5_.l;           \
    P_##bh[6] = s6_.h; P_##bl[6] = s6_.l; P_##bh[7] = s7_.h; P_##bl[7] = s7_.l; } while (0)
#define OMM(P_) do {                                                                   \
    acc = __builtin_amdgcn_mfma_f32_16x16x32_bf16(P_##ah, P_##bh, acc, 0, 0, 0);       \
    acc = __builtin_amdgcn_mfma_f32_16x16x32_bf16(P_##ah, P_##bl, acc, 0, 0, 0);       \
    acc = __builtin_amdgcn_mfma_f32_16x16x32_bf16(P_##al, P_##bh, acc, 0, 0, 0); } while (0)
#define OSTEP(P_, KN) do { OMM(P_); if ((KN) < 16) OLD(P_, KN); } while (0)

        OLD(A_, 0); OLD(B_, 1);
        OSTEP(A_, 2);  OSTEP(B_, 3);  OSTEP(A_, 4);  OSTEP(B_, 5);
        OSTEP(A_, 6);  OSTEP(B_, 7);  OSTEP(A_, 8);  OSTEP(B_, 9);
        OSTEP(A_, 10); OSTEP(B_, 11); OSTEP(A_, 12); OSTEP(B_, 13);
        OSTEP(A_, 14); OSTEP(B_, 15); OSTEP(A_, 16); OSTEP(B_, 17);
#undef OLD
#undef OMM
#undef OSTEP

#pragma unroll
        for (int r = 0; r < 4; ++r) {
            const int row = by * 16 + (lane >> 4) * 4 + r;
            out[row * DM + bcol] = acc[r] + bout[bcol];
        }
    }
}

// ================= Persistent mega-kernel =================
__global__ __launch_bounds__(256, 4) void k_mega(
    const float* __restrict__ x,
    const float* __restrict__ Wkkq, const float* __restrict__ Wv1,
    const float* __restrict__ Wv2,  const float* __restrict__ Wout,
    const float* __restrict__ bkkq, const float* __restrict__ bv1,
    const float* __restrict__ bv2,  const float* __restrict__ bout,
    float* __restrict__ k1, float* __restrict__ k2, float* __restrict__ qv,
    float* __restrict__ sv1, float* __restrict__ v2o, float* __restrict__ z,
    float* __restrict__ Ekk, float* __restrict__ Eqk,
    float* __restrict__ P,   float* __restrict__ gP,
    float* __restrict__ out, unsigned* __restrict__ bar)
{
    const int tid = threadIdx.x, bid = blockIdx.x, nblk = gridDim.x;

    phase1(x, Wkkq, Wv1, Wv2, bkkq, bv1, bv2, k1, k2, qv, sv1, v2o, bid, nblk, tid);
    grid_barrier(bar, 1u * nblk, tid);
    phase2(k1, k2, qv, sv1, Ekk, Eqk, P, gP, bid, nblk, tid);
    grid_barrier(bar, 2u * nblk, tid);
    phase3(Ekk, Eqk, sv1, v2o, P, gP, z, bid, nblk, tid);
    grid_barrier(bar, 3u * nblk, tid);
    phase4(z, Wout, bout, out, bid, nblk, tid);
}

// ================= Fallback standalone kernels (R7 pipeline) =================
__global__ __launch_bounds__(256) void k_p1(
    const float* __restrict__ x,
    const float* __restrict__ Wkkq, const float* __restrict__ Wv1,
    const float* __restrict__ Wv2,
    const float* __restrict__ bkkq, const float* __restrict__ bv1,
    const float* __restrict__ bv2,
    float* __restrict__ k1, float* __restrict__ k2, float* __restrict__ qv,
    float* __restrict__ sv1, float* __restrict__ v2o)
{
    phase1(x, Wkkq, Wv1, Wv2, bkkq, bv1, bv2, k1, k2, qv, sv1, v2o,
           blockIdx.x, gridDim.x, threadIdx.x);
}

__global__ __launch_bounds__(256) void k_p2(
    const float* __restrict__ k1, const float* __restrict__ k2,
    const float* __restrict__ qv, const float* __restrict__ sv1,
    float* __restrict__ Ekk, float* __restrict__ Eqk,
    float* __restrict__ P, float* __restrict__ gP)
{
    phase2(k1, k2, qv, sv1, Ekk, Eqk, P, gP, blockIdx.x, gridDim.x, threadIdx.x);
}

__global__ __launch_bounds__(256) void k_p3(
    const float* __restrict__ Ekk, const float* __restrict__ Eqk,
    const float* __restrict__ sv1, const float* __restrict__ v2o,
    const float* __restrict__ P,   const float* __restrict__ gP,
    float* __restrict__ z)
{
    phase3(Ekk, Eqk, sv1, v2o, P, gP, z, blockIdx.x, gridDim.x, threadIdx.x);
}

__global__ __launch_bounds__(256) void k_p4(
    const float* __restrict__ z, const float* __restrict__ Wout,
    const float* __restrict__ bout, float* __restrict__ out)
{
    phase4(z, Wout, bout, out, blockIdx.x, gridDim.x, threadIdx.x);
}

extern "C" void kernel_launch(void* const* d_in, const int* in_sizes, int n_in,
                              void* d_out, int out_size, void* d_ws, size_t ws_size,
                              hipStream_t stream) {
    const float* x    = (const float*)d_in[0];
    const float* Wkkq = (const float*)d_in[1];
    const float* bkkq = (const float*)d_in[2];
    const float* Wv1  = (const float*)d_in[3];
    const float* bv1  = (const float*)d_in[4];
    const float* Wv2  = (const float*)d_in[5];
    const float* bv2  = (const float*)d_in[6];
    const float* Wout = (const float*)d_in[7];
    const float* bout = (const float*)d_in[8];
    float* out = (float*)d_out;

    float* ws  = (float*)d_ws;
    float* k1  = ws;
    float* k2  = k1  + 196608;
    float* qv  = k2  + 196608;
    float* sv1 = qv  + 196608;
    float* v2  = sv1 + 196608;
    float* z   = v2  + 196608;
    float* Ekk = z   + 196608;
    float* Eqk = Ekk + 589824;
    float* P   = Eqk + 589824;            // 16*6*64*192
    float* gP  = P   + 1179648;           // 16*6*192
    unsigned* bar = (unsigned*)(gP + 18432);

    // zero the barrier counter (graph-capturable memset node)
    hipMemsetAsync(bar, 0, 64, stream);

    void* args[] = {
        (void*)&x, (void*)&Wkkq, (void*)&Wv1, (void*)&Wv2, (void*)&Wout,
        (void*)&bkkq, (void*)&bv1, (void*)&bv2, (void*)&bout,
        (void*)&k1, (void*)&k2, (void*)&qv, (void*)&sv1, (void*)&v2,
        (void*)&z, (void*)&Ekk, (void*)&Eqk, (void*)&P, (void*)&gP,
        (void*)&out, (void*)&bar
    };

    hipError_t err = hipLaunchCooperativeKernel((void*)k_mega, dim3(1024), dim3(256),
                                                args, 0, stream);
    if (err != hipSuccess) {
        (void)hipGetLastError();
        err = hipLaunchCooperativeKernel((void*)k_mega, dim3(512), dim3(256),
                                         args, 0, stream);
    }
    if (err != hipSuccess) {
        (void)hipGetLastError();   // fall back to the proven 4-kernel pipeline
        k_p1<<<dim3(960),  256, 0, stream>>>(x, Wkkq, Wv1, Wv2, bkkq, bv1, bv2,
                                             k1, k2, qv, sv1, v2);
        k_p2<<<dim3(1152), 256, 0, stream>>>(k1, k2, qv, sv1, Ekk, Eqk, P, gP);
        k_p3<<<dim3(1024), 256, 0, stream>>>(Ekk, Eqk, sv1, v2, P, gP, z);
        k_p4<<<dim3(192),  256, 0, stream>>>(z, Wout, bout, out);
    }
}

// Round 13
// 88.060 us; speedup vs baseline: 5.3901x; 5.3901x over previous
//
#include <hip/hip_runtime.h>
#include <hip/hip_bf16.h>

// Trittention, factorized:
//   z[q,h] = sum_{t<=q} Eqk[q,t]*v2[t,h]*G_q[t,h] / sum_{t<=q} Eqk[q,t]*g_q[t]
//   G_q[t,h] = sum_{s<=q} Ekk[s,t]*silu(v1)[s,h]   (prefix over s)
// R12: FINAL revert to the proven R7 4-kernel pipeline (83.9us).
// Persistent-kernel fusion refuted on this platform: grid barriers cost
// >=85us each regardless of implementation (R9: cg 272us, R10: atomic+
// sleep(1) 285us, R11: leader-fence+sleep(16) 474us). The 4-node DAG
// p1->p2->p3->p4 is the minimal structure (each phase consumes all of the
// previous phase's output).

constexpr int Tn = 192;
constexpr int DM = 512;
constexpr int NH = 8;
constexpr int HD = 64;
constexpr int TT = Tn * Tn;
constexpr int NCc = 6;           // chunks of 32 s-rows
constexpr int CSc = 32;

typedef __bf16 bf16_t;
typedef bf16_t bf16x8 __attribute__((ext_vector_type(8)));
typedef float  f32x4  __attribute__((ext_vector_type(4)));

struct bf16pair { bf16_t h, l; };
__device__ __forceinline__ bf16pair split_bf16(float v) {
    bf16pair r;
    r.h = (bf16_t)v;
    r.l = (bf16_t)(v - (float)r.h);
    return r;
}

// ================= Phase 1: projection GEMM =================
// [384x512] @ [512x2560]; 960 tiles of 32x32, 4 waves (16x16 each),
// 2-deep register prefetch, fp32 read + in-reg bf16 hi/lo split
// (A.B ~ Ah.Bh + Ah.Bl + Al.Bh, fp32 accum; rel err ~2^-16).
__device__ __forceinline__ void phase1(
    const float* __restrict__ x,
    const float* __restrict__ Wkkq, const float* __restrict__ Wv1,
    const float* __restrict__ Wv2,
    const float* __restrict__ bkkq, const float* __restrict__ bv1,
    const float* __restrict__ bv2,
    float* __restrict__ k1, float* __restrict__ k2, float* __restrict__ qv,
    float* __restrict__ sv1, float* __restrict__ v2o,
    int bid0, int nblk, int tid)
{
    const int w = tid >> 6, lane = tid & 63;
    const int wm = w & 1, wn = w >> 1;
    const int lr = lane & 15, lk = (lane >> 4) * 8;

    for (int wi = bid0; wi < 960; wi += nblk) {
        const int bx = wi % 80, by = wi / 80;

        const float* Wp; int ldw, cloc;
        if (bx < 48)      { Wp = Wkkq; ldw = 1536; cloc = bx * 32; }
        else if (bx < 64) { Wp = Wv1;  ldw = 512;  cloc = bx * 32 - 1536; }
        else              { Wp = Wv2;  ldw = 512;  cloc = bx * 32 - 2048; }

        const int arow = by * 32 + wm * 16 + lr;
        const int bcol = cloc + wn * 16 + lr;
        const float* xrow = x + arow * DM;

        f32x4 acc = {0.f,0.f,0.f,0.f};
        bf16x8 A_ah, A_al, A_bh, A_bl;
        bf16x8 B_ah, B_al, B_bh, B_bl;

#define PLD(P_, KS) do { const int ko_ = (KS) * 32 + lk;                                  \
    const float4 u0 = *reinterpret_cast<const float4*>(&xrow[ko_]);                       \
    const float4 u1 = *reinterpret_cast<const float4*>(&xrow[ko_ + 4]);                   \
    const float* wp_ = Wp + ko_ * ldw + bcol;                                             \
    const float w0_ = wp_[0],       w1_ = wp_[ldw],     w2_ = wp_[2 * ldw];               \
    const float w3_ = wp_[3 * ldw], w4_ = wp_[4 * ldw], w5_ = wp_[5 * ldw];               \
    const float w6_ = wp_[6 * ldw], w7_ = wp_[7 * ldw];                                   \
    bf16pair t0_ = split_bf16(u0.x), t1_ = split_bf16(u0.y);                              \
    bf16pair t2_ = split_bf16(u0.z), t3_ = split_bf16(u0.w);                              \
    bf16pair t4_ = split_bf16(u1.x), t5_ = split_bf16(u1.y);                              \
    bf16pair t6_ = split_bf16(u1.z), t7_ = split_bf16(u1.w);                              \
    P_##ah[0] = t0_.h; P_##al[0] = t0_.l; P_##ah[1] = t1_.h; P_##al[1] = t1_.l;           \
    P_##ah[2] = t2_.h; P_##al[2] = t2_.l; P_##ah[3] = t3_.h; P_##al[3] = t3_.l;           \
    P_##ah[4] = t4_.h; P_##al[4] = t4_.l; P_##ah[5] = t5_.h; P_##al[5] = t5_.l;           \
    P_##ah[6] = t6_.h; P_##al[6] = t6_.l; P_##ah[7] = t7_.h; P_##al[7] = t7_.l;           \
    bf16pair s0_ = split_bf16(w0_), s1_ = split_bf16(w1_);                                \
    bf16pair s2_ = split_bf16(w2_), s3_ = split_bf16(w3_);                                \
    bf16pair s4_ = split_bf16(w4_), s5_ = split_bf16(w5_);                                \
    bf16pair s6_ = split_bf16(w6_), s7_ = split_bf16(w7_);                                \
    P_##bh[0] = s0_.h; P_##bl[0] = s0_.l; P_##bh[1] = s1_.h; P_##bl[1] = s1_.l;           \
    P_##bh[2] = s2_.h; P_##bl[2] = s2_.l; P_##bh[3] = s3_.h; P_##bl[3] = s3_.l;           \
    P_##bh[4] = s4_.h; P_##bl[4] = s4_.l; P_##bh[5] = s5_.h; P_##bl[5] = s5_.l;           \
    P_##bh[6] = s6_.h; P_##bl[6] = s6_.l; P_##bh[7] = s7_.h; P_##bl[7] = s7_.l; } while (0)
#define PMM(P_) do {                                                                    \
    acc = __builtin_amdgcn_mfma_f32_16x16x32_bf16(P_##ah, P_##bh, acc, 0, 0, 0);        \
    acc = __builtin_amdgcn_mfma_f32_16x16x32_bf16(P_##ah, P_##bl, acc, 0, 0, 0);        \
    acc = __builtin_amdgcn_mfma_f32_16x16x32_bf16(P_##al, P_##bh, acc, 0, 0, 0); } while (0)
#define PSTEP(P_, KN) do { PMM(P_); if ((KN) < 16) PLD(P_, KN); } while (0)

        PLD(A_, 0); PLD(B_, 1);
        PSTEP(A_, 2);  PSTEP(B_, 3);  PSTEP(A_, 4);  PSTEP(B_, 5);
        PSTEP(A_, 6);  PSTEP(B_, 7);  PSTEP(A_, 8);  PSTEP(B_, 9);
        PSTEP(A_, 10); PSTEP(B_, 11); PSTEP(A_, 12); PSTEP(B_, 13);
        PSTEP(A_, 14); PSTEP(B_, 15); PSTEP(A_, 16); PSTEP(B_, 17);
#undef PLD
#undef PMM
#undef PSTEP

        const int gcol = bx * 32 + wn * 16 + lr;
#pragma unroll
        for (int r = 0; r < 4; ++r) {
            const int row = by * 32 + wm * 16 + (lane >> 4) * 4 + r;
            const int b = row / Tn, t = row % Tn;
            const float a = acc[r];
            if (gcol < 1536) {
                const float val = a + bkkq[gcol];
                const int third = gcol >> 9, nh = gcol & 511, n = nh >> 6, hh = nh & 63;
                float* dst = (third == 0) ? k1 : (third == 1) ? k2 : qv;
                dst[((b * NH + n) * Tn + t) * HD + hh] = val;
            } else if (gcol < 2048) {
                const int c = gcol - 1536;
                float val = a + bv1[c];
                val = val / (1.f + __expf(-val));
                sv1[((b * NH + (c >> 6)) * Tn + t) * HD + (c & 63)] = val;
            } else {
                const int c = gcol - 2048;
                v2o[((b * NH + (c >> 6)) * Tn + t) * HD + (c & 63)] = a + bv2[c];
            }
        }
    }
}

// ================= Phase 2: exp tables + chunk partials =================
__device__ __forceinline__ void phase2(
    const float* __restrict__ k1, const float* __restrict__ k2,
    const float* __restrict__ qv, const float* __restrict__ sv1,
    float* __restrict__ Ekk, float* __restrict__ Eqk,
    float* __restrict__ P, float* __restrict__ gP,
    int bid0, int nblk, int tid)
{
    __shared__ float As[32][65], Bs[32][65], Vs[32][65];
    __shared__ float Es[32][33];

    for (int wi = bid0; wi < 1152; wi += nblk) {
        const int bn = wi / 72;
        int bx = wi % 72;
        const int mat = (bx >= 36) ? 1 : 0;
        if (mat) bx -= 36;
        const int st = bx / 6, tt = bx % 6;
        const float* A  = ((mat == 0) ? k1 : qv) + bn * Tn * HD;
        const float* Bm = k2 + bn * Tn * HD;
        float* E = ((mat == 0) ? Ekk : Eqk) + bn * TT;

        for (int i = tid; i < 32 * 64; i += 256) {
            const int r = i >> 6, h = i & 63;
            As[r][h] = A[(st * 32 + r) * HD + h];
            Bs[r][h] = Bm[(tt * 32 + r) * HD + h];
            if (mat == 0) Vs[r][h] = sv1[bn * Tn * HD + (st * 32 + r) * HD + h];
        }
        __syncthreads();

        const int tx = tid & 15, ty = tid >> 4;
        const int r0 = ty * 2, c0 = tx * 2;
        float a00 = 0.f, a01 = 0.f, a10 = 0.f, a11 = 0.f;
#pragma unroll
        for (int h = 0; h < 64; ++h) {
            const float ar0 = As[r0][h], ar1 = As[r0 + 1][h];
            const float bc0 = Bs[c0][h], bc1 = Bs[c0 + 1][h];
            a00 = fmaf(ar0, bc0, a00); a01 = fmaf(ar0, bc1, a01);
            a10 = fmaf(ar1, bc0, a10); a11 = fmaf(ar1, bc1, a11);
        }
        constexpr float sc = 1.f / 64.f;
        const float e00 = __expf(a00 * sc), e01 = __expf(a01 * sc);
        const float e10 = __expf(a10 * sc), e11 = __expf(a11 * sc);
        const int gr = st * 32 + r0, gc = tt * 32 + c0;
        E[(gr)     * Tn + gc]     = e00;
        E[(gr)     * Tn + gc + 1] = e01;
        E[(gr + 1) * Tn + gc]     = e10;
        E[(gr + 1) * Tn + gc + 1] = e11;

        if (mat == 0) {
            Es[r0][c0] = e00; Es[r0][c0 + 1] = e01;
            Es[r0 + 1][c0] = e10; Es[r0 + 1][c0 + 1] = e11;
            __syncthreads();

            const int h   = tid >> 2;
            const int tp0 = (tid & 3) * 8;
            float p[8] = {0.f,0.f,0.f,0.f,0.f,0.f,0.f,0.f};
            for (int s = 0; s < 32; ++s) {
                const float a = Vs[s][h];
#pragma unroll
                for (int j = 0; j < 8; ++j) p[j] = fmaf(Es[s][tp0 + j], a, p[j]);
            }
            float* pd = P + ((bn * NCc + st) * HD + h) * Tn + tt * 32 + tp0;
            *reinterpret_cast<float4*>(&pd[0]) = make_float4(p[0], p[1], p[2], p[3]);
            *reinterpret_cast<float4*>(&pd[4]) = make_float4(p[4], p[5], p[6], p[7]);

            if (tid < 32) {
                float s = 0.f;
#pragma unroll
                for (int ss = 0; ss < 32; ++ss) s += Es[ss][tid];
                gP[(bn * NCc + st) * Tn + tt * 32 + tid] = s;
            }
        }
        __syncthreads();   // protect As/Bs/Vs/Es before next grid-stride iter
    }
}

// ================= Phase 3: attention from chunk partials =================
__device__ __forceinline__ void phase3(
    const float* __restrict__ Ekk, const float* __restrict__ Eqk,
    const float* __restrict__ sv1, const float* __restrict__ v2o,
    const float* __restrict__ P,   const float* __restrict__ gP,
    float* __restrict__ z,
    int bid0, int nblk, int tid)
{
    const int tg = tid & 15, hh = tid >> 4;
    for (int wi = bid0; wi < 1024; wi += nblk) {
        const int hq = wi & 3;
        const int qt = (wi >> 2) & 15;
        const int bn = wi >> 6;
        const int b = bn >> 3, n = bn & 7;
        const int h  = hq * 16 + hh;
        const int t0 = tg * 12;
        const int q0 = qt * 12;
        const int cb = q0 >> 5;

        const float* ekk = Ekk + bn * TT;
        const float* eqk = Eqk + bn * TT;
        const float* s1  = sv1 + bn * Tn * HD;
        const float* vv  = v2o + bn * Tn * HD;

        float G[12], g[12];
#pragma unroll
        for (int j = 0; j < 12; ++j) { G[j] = 0.f; g[j] = 0.f; }

        for (int c = 0; c < cb; ++c) {
            const float* pb = P  + ((bn * NCc + c) * HD + h) * Tn + t0;
            const float* gb = gP + (bn * NCc + c) * Tn + t0;
#pragma unroll
            for (int jj = 0; jj < 3; ++jj) {
                const float4 pv = *reinterpret_cast<const float4*>(&pb[4 * jj]);
                G[4*jj+0] += pv.x; G[4*jj+1] += pv.y; G[4*jj+2] += pv.z; G[4*jj+3] += pv.w;
                const float4 gv = *reinterpret_cast<const float4*>(&gb[4 * jj]);
                g[4*jj+0] += gv.x; g[4*jj+1] += gv.y; g[4*jj+2] += gv.z; g[4*jj+3] += gv.w;
            }
        }

        float vvr[12];
#pragma unroll
        for (int j = 0; j < 12; ++j) vvr[j] = vv[(t0 + j) * HD + h];

        for (int s = CSc * cb; s < q0; ++s) {
            const float a = s1[s * HD + h];
            const float* ek = ekk + s * Tn + t0;
#pragma unroll
            for (int jj = 0; jj < 3; ++jj) {
                const float4 ev = *reinterpret_cast<const float4*>(&ek[4 * jj]);
                G[4*jj+0] = fmaf(ev.x, a, G[4*jj+0]); g[4*jj+0] += ev.x;
                G[4*jj+1] = fmaf(ev.y, a, G[4*jj+1]); g[4*jj+1] += ev.y;
                G[4*jj+2] = fmaf(ev.z, a, G[4*jj+2]); g[4*jj+2] += ev.z;
                G[4*jj+3] = fmaf(ev.w, a, G[4*jj+3]); g[4*jj+3] += ev.w;
            }
        }

        for (int q = q0; q < q0 + 12; ++q) {
            {
                const float a = s1[q * HD + h];
                const float* ek = ekk + q * Tn + t0;
#pragma unroll
                for (int jj = 0; jj < 3; ++jj) {
                    const float4 ev = *reinterpret_cast<const float4*>(&ek[4 * jj]);
                    G[4*jj+0] = fmaf(ev.x, a, G[4*jj+0]); g[4*jj+0] += ev.x;
                    G[4*jj+1] = fmaf(ev.y, a, G[4*jj+1]); g[4*jj+1] += ev.y;
                    G[4*jj+2] = fmaf(ev.z, a, G[4*jj+2]); g[4*jj+2] += ev.z;
                    G[4*jj+3] = fmaf(ev.w, a, G[4*jj+3]); g[4*jj+3] += ev.w;
                }
            }
            const float* eq = eqk + q * Tn + t0;
            float zp = 0.f, Zp = 0.f;
#pragma unroll
            for (int jj = 0; jj < 3; ++jj) {
                const float4 ev = *reinterpret_cast<const float4*>(&eq[4 * jj]);
                const float e0 = (t0 + 4*jj + 0 <= q) ? ev.x : 0.f;
                const float e1 = (t0 + 4*jj + 1 <= q) ? ev.y : 0.f;
                const float e2 = (t0 + 4*jj + 2 <= q) ? ev.z : 0.f;
                const float e3 = (t0 + 4*jj + 3 <= q) ? ev.w : 0.f;
                zp = fmaf(e0 * vvr[4*jj+0], G[4*jj+0], zp); Zp = fmaf(e0, g[4*jj+0], Zp);
                zp = fmaf(e1 * vvr[4*jj+1], G[4*jj+1], zp); Zp = fmaf(e1, g[4*jj+1], Zp);
                zp = fmaf(e2 * vvr[4*jj+2], G[4*jj+2], zp); Zp = fmaf(e2, g[4*jj+2], Zp);
                zp = fmaf(e3 * vvr[4*jj+3], G[4*jj+3], zp); Zp = fmaf(e3, g[4*jj+3], Zp);
            }
            zp += __shfl_xor(zp, 1); zp += __shfl_xor(zp, 2);
            zp += __shfl_xor(zp, 4); zp += __shfl_xor(zp, 8);
            Zp += __shfl_xor(Zp, 1); Zp += __shfl_xor(Zp, 2);
            Zp += __shfl_xor(Zp, 4); Zp += __shfl_xor(Zp, 8);
            if (tg == 0) z[((b * Tn + q) * NH + n) * HD + h] = zp / Zp;
        }
    }
}

// ================= Phase 4: output projection =================
__device__ __forceinline__ void phase4(
    const float* __restrict__ z, const float* __restrict__ Wout,
    const float* __restrict__ bout, float* __restrict__ out,
    int bid0, int nblk, int tid)
{
    const int w = tid >> 6, lane = tid & 63;
    const int lr = lane & 15, lk = (lane >> 4) * 8;
    for (int wi = bid0; wi < 192; wi += nblk) {
        const int bx = wi % 8, by = wi / 8;
        const int arow = by * 16 + lr;
        const int bcol = bx * 64 + w * 16 + lr;
        const float* zrow = z + arow * DM;

        f32x4 acc = {0.f,0.f,0.f,0.f};
        bf16x8 A_ah, A_al, A_bh, A_bl;
        bf16x8 B_ah, B_al, B_bh, B_bl;

#define OLD(P_, KS) do { const int ko_ = (KS) * 32 + lk;                                  \
    const float4 u0 = *reinterpret_cast<const float4*>(&zrow[ko_]);                       \
    const float4 u1 = *reinterpret_cast<const float4*>(&zrow[ko_ + 4]);                   \
    const float* wp_ = Wout + ko_ * DM + bcol;                                            \
    const float w0_ = wp_[0],      w1_ = wp_[DM],     w2_ = wp_[2 * DM];                  \
    const float w3_ = wp_[3 * DM], w4_ = wp_[4 * DM], w5_ = wp_[5 * DM];                  \
    const float w6_ = wp_[6 * DM], w7_ = wp_[7 * DM];                                     \
    bf16pair t0_ = split_bf16(u0.x), t1_ = split_bf16(u0.y);                              \
    bf16pair t2_ = split_bf16(u0.z), t3_ = split_bf16(u0.w);                              \
    bf16pair t4_ = split_bf16(u1.x), t5_ = split_bf16(u1.y);                              \
    bf16pair t6_ = split_bf16(u1.z), t7_ = split_bf16(u1.w);                              \
    P_##ah[0] = t0_.h; P_##al[0] = t0_.l; P_##ah[1] = t1_.h; P_##al[1] = t1_.l;           \
    P_##ah[2] = t2_.h; P_##al[2] = t2_.l; P_##ah[3] = t3_.h; P_##al[3] = t3_.l;           \
    P_##ah[4] = t4_.h; P_##al[4] = t4_.l; P_##ah[5] = t5_.h; P_##al[5] = t5_.l;           \
    P_##ah[6] = t6_.h; P_##al[6] = t6_.l; P_##ah[7] = t7_.h; P_##al[7] = t7_.l;           \
    bf16pair s0_ = split_bf16(w0_), s1_ = split_bf16(w1_);                                \
    bf16pair s2_ = split_bf16(w2_), s3_ = split_bf16(w3_);                                \
    bf16pair s4_ = split_bf16(w4_), s5_ = split_bf16(w5_);                                \
    bf16pair s6_ = split_bf16(w6_), s7_ = split_bf16(w7_);                                \
    P_##bh[0] = s0_.h; P_##bl[0] = s0_.l; P_##bh[1] = s1_.h; P_##bl[1] = s1_.l;           \
    P_##bh[2] = s2_.h; P_##bl[2] = s2_.l; P_##bh[3] = s3_.h; P_##bl[3] = s3_.l;           \
    P_##bh[4] = s4_.h; P_##bl[4] = s4_.l; P_##bh[5] = s5_.h; P_##bl[5] = s5_.l;           \
    P_##bh[6] = s6_.h; P_##bl[6] = s6_.l; P_##bh[7] = s7_.h; P_##bl[7] = s7_.l; } while (0)
#define OMM(P_) do {                                                                   \
    acc = __builtin_amdgcn_mfma_f32_16x16x32_bf16(P_##ah, P_##bh, acc, 0, 0, 0);       \
    acc = __builtin_amdgcn_mfma_f32_16x16x32_bf16(P_##ah, P_##bl, acc, 0, 0, 0);       \
    acc = __builtin_amdgcn_mfma_f32_16x16x32_bf16(P_##al, P_##bh, acc, 0, 0, 0); } while (0)
#define OSTEP(P_, KN) do { OMM(P_); if ((KN) < 16) OLD(P_, KN); } while (0)

        OLD(A_, 0); OLD(B_, 1);
        OSTEP(A_, 2);  OSTEP(B_, 3);  OSTEP(A_, 4);  OSTEP(B_, 5);
        OSTEP(A_, 6);  OSTEP(B_, 7);  OSTEP(A_, 8);  OSTEP(B_, 9);
        OSTEP(A_, 10); OSTEP(B_, 11); OSTEP(A_, 12); OSTEP(B_, 13);
        OSTEP(A_, 14); OSTEP(B_, 15); OSTEP(A_, 16); OSTEP(B_, 17);
#undef OLD
#undef OMM
#undef OSTEP

#pragma unroll
        for (int r = 0; r < 4; ++r) {
            const int row = by * 16 + (lane >> 4) * 4 + r;
            out[row * DM + bcol] = acc[r] + bout[bcol];
        }
    }
}

// ================= Standalone kernels (4-node pipeline) =================
__global__ __launch_bounds__(256) void k_p1(
    const float* __restrict__ x,
    const float* __restrict__ Wkkq, const float* __restrict__ Wv1,
    const float* __restrict__ Wv2,
    const float* __restrict__ bkkq, const float* __restrict__ bv1,
    const float* __restrict__ bv2,
    float* __restrict__ k1, float* __restrict__ k2, float* __restrict__ qv,
    float* __restrict__ sv1, float* __restrict__ v2o)
{
    phase1(x, Wkkq, Wv1, Wv2, bkkq, bv1, bv2, k1, k2, qv, sv1, v2o,
           blockIdx.x, gridDim.x, threadIdx.x);
}

__global__ __launch_bounds__(256) void k_p2(
    const float* __restrict__ k1, const float* __restrict__ k2,
    const float* __restrict__ qv, const float* __restrict__ sv1,
    float* __restrict__ Ekk, float* __restrict__ Eqk,
    float* __restrict__ P, float* __restrict__ gP)
{
    phase2(k1, k2, qv, sv1, Ekk, Eqk, P, gP, blockIdx.x, gridDim.x, threadIdx.x);
}

__global__ __launch_bounds__(256) void k_p3(
    const float* __restrict__ Ekk, const float* __restrict__ Eqk,
    const float* __restrict__ sv1, const float* __restrict__ v2o,
    const float* __restrict__ P,   const float* __restrict__ gP,
    float* __restrict__ z)
{
    phase3(Ekk, Eqk, sv1, v2o, P, gP, z, blockIdx.x, gridDim.x, threadIdx.x);
}

__global__ __launch_bounds__(256) void k_p4(
    const float* __restrict__ z, const float* __restrict__ Wout,
    const float* __restrict__ bout, float* __restrict__ out)
{
    phase4(z, Wout, bout, out, blockIdx.x, gridDim.x, threadIdx.x);
}

extern "C" void kernel_launch(void* const* d_in, const int* in_sizes, int n_in,
                              void* d_out, int out_size, void* d_ws, size_t ws_size,
                              hipStream_t stream) {
    const float* x    = (const float*)d_in[0];
    const float* Wkkq = (const float*)d_in[1];
    const float* bkkq = (const float*)d_in[2];
    const float* Wv1  = (const float*)d_in[3];
    const float* bv1  = (const float*)d_in[4];
    const float* Wv2  = (const float*)d_in[5];
    const float* bv2  = (const float*)d_in[6];
    const float* Wout = (const float*)d_in[7];
    const float* bout = (const float*)d_in[8];
    float* out = (float*)d_out;

    float* ws  = (float*)d_ws;
    float* k1  = ws;
    float* k2  = k1  + 196608;
    float* qv  = k2  + 196608;
    float* sv1 = qv  + 196608;
    float* v2  = sv1 + 196608;
    float* z   = v2  + 196608;
    float* Ekk = z   + 196608;
    float* Eqk = Ekk + 589824;
    float* P   = Eqk + 589824;            // 16*6*64*192
    float* gP  = P   + 1179648;           // 16*6*192

    k_p1<<<dim3(960),  256, 0, stream>>>(x, Wkkq, Wv1, Wv2, bkkq, bv1, bv2,
                                         k1, k2, qv, sv1, v2);
    k_p2<<<dim3(1152), 256, 0, stream>>>(k1, k2, qv, sv1, Ekk, Eqk, P, gP);
    k_p3<<<dim3(1024), 256, 0, stream>>>(Ekk, Eqk, sv1, v2, P, gP, z);
    k_p4<<<dim3(192),  256, 0, stream>>>(z, Wout, bout, out);
}

// Round 14
// 84.027 us; speedup vs baseline: 5.6488x; 1.0480x over previous
//
#include <hip/hip_runtime.h>
#include <hip/hip_bf16.h>

// Trittention, factorized:
//   z[q,h] = sum_{t<=q} Eqk[q,t]*v2[t,h]*G_q[t,h] / sum_{t<=q} Eqk[q,t]*g_q[t]
//   G_q[t,h] = sum_{s<=q} Ekk[s,t]*silu(v1)[s,h]   (prefix over s)
// R13 FINAL: exact resubmission of the R7 pipeline (best measured: 83.9us).
// 4-node DAG projm -> scoresP -> attn2 -> outm; direct-mapped grids.
// Floor composition: ~25-30us work + ~14us x 4 node boundaries.
// Refuted alternatives: in-kernel grid sync (cg 272us / atomic 285us /
// leader-fence 474us; >=85us per cross-XCD barrier), node-count reduction
// (every phase consumes ALL of the previous phase's output).

constexpr int Tn = 192;
constexpr int DM = 512;
constexpr int NH = 8;
constexpr int HD = 64;
constexpr int TT = Tn * Tn;
constexpr int NCc = 6;           // chunks of 32 s-rows
constexpr int CSc = 32;

typedef __bf16 bf16_t;
typedef bf16_t bf16x8 __attribute__((ext_vector_type(8)));
typedef float  f32x4  __attribute__((ext_vector_type(4)));

struct bf16pair { bf16_t h, l; };
__device__ __forceinline__ bf16pair split_bf16(float v) {
    bf16pair r;
    r.h = (bf16_t)v;
    r.l = (bf16_t)(v - (float)r.h);
    return r;
}

// ---------------- Kernel 1: MFMA projection GEMM (fp32 in, in-reg split) ----
// [384x512] @ [512x2560]; 32x32 tile, 4 waves (16x16 quadrant each),
// 2-deep register prefetch. W read as 8 stride-ldw dwords (coalesced per
// 16-lane group), x read as 2x float4.
__global__ __launch_bounds__(256) void k_projm(
    const float* __restrict__ x,
    const float* __restrict__ Wkkq, const float* __restrict__ Wv1,
    const float* __restrict__ Wv2,
    const float* __restrict__ bkkq, const float* __restrict__ bv1,
    const float* __restrict__ bv2,
    float* __restrict__ k1, float* __restrict__ k2, float* __restrict__ qv,
    float* __restrict__ sv1, float* __restrict__ v2o)
{
    const int bx = blockIdx.x, by = blockIdx.y;   // 80 col-tiles x 12 row-tiles
    const int tid = threadIdx.x;
    const int w = tid >> 6, lane = tid & 63;
    const int wm = w & 1, wn = w >> 1;
    const int lr = lane & 15, lk = (lane >> 4) * 8;

    const float* Wp; int ldw, cloc;
    if (bx < 48)      { Wp = Wkkq; ldw = 1536; cloc = bx * 32; }
    else if (bx < 64) { Wp = Wv1;  ldw = 512;  cloc = bx * 32 - 1536; }
    else              { Wp = Wv2;  ldw = 512;  cloc = bx * 32 - 2048; }

    const int arow = by * 32 + wm * 16 + lr;
    const int bcol = cloc + wn * 16 + lr;
    const float* xrow = x + arow * DM;

    f32x4 acc = {0.f,0.f,0.f,0.f};
    bf16x8 A_ah, A_al, A_bh, A_bl;
    bf16x8 B_ah, B_al, B_bh, B_bl;

#define PLD(P_, KS) do { const int ko_ = (KS) * 32 + lk;                                  \
    const float4 u0 = *reinterpret_cast<const float4*>(&xrow[ko_]);                       \
    const float4 u1 = *reinterpret_cast<const float4*>(&xrow[ko_ + 4]);                   \
    const float* wp_ = Wp + ko_ * ldw + bcol;                                             \
    const float w0_ = wp_[0],       w1_ = wp_[ldw],     w2_ = wp_[2 * ldw];               \
    const float w3_ = wp_[3 * ldw], w4_ = wp_[4 * ldw], w5_ = wp_[5 * ldw];               \
    const float w6_ = wp_[6 * ldw], w7_ = wp_[7 * ldw];                                   \
    bf16pair t0_ = split_bf16(u0.x), t1_ = split_bf16(u0.y);                              \
    bf16pair t2_ = split_bf16(u0.z), t3_ = split_bf16(u0.w);                              \
    bf16pair t4_ = split_bf16(u1.x), t5_ = split_bf16(u1.y);                              \
    bf16pair t6_ = split_bf16(u1.z), t7_ = split_bf16(u1.w);                              \
    P_##ah[0] = t0_.h; P_##al[0] = t0_.l; P_##ah[1] = t1_.h; P_##al[1] = t1_.l;           \
    P_##ah[2] = t2_.h; P_##al[2] = t2_.l; P_##ah[3] = t3_.h; P_##al[3] = t3_.l;           \
    P_##ah[4] = t4_.h; P_##al[4] = t4_.l; P_##ah[5] = t5_.h; P_##al[5] = t5_.l;           \
    P_##ah[6] = t6_.h; P_##al[6] = t6_.l; P_##ah[7] = t7_.h; P_##al[7] = t7_.l;           \
    bf16pair s0_ = split_bf16(w0_), s1_ = split_bf16(w1_);                                \
    bf16pair s2_ = split_bf16(w2_), s3_ = split_bf16(w3_);                                \
    bf16pair s4_ = split_bf16(w4_), s5_ = split_bf16(w5_);                                \
    bf16pair s6_ = split_bf16(w6_), s7_ = split_bf16(w7_);                                \
    P_##bh[0] = s0_.h; P_##bl[0] = s0_.l; P_##bh[1] = s1_.h; P_##bl[1] = s1_.l;           \
    P_##bh[2] = s2_.h; P_##bl[2] = s2_.l; P_##bh[3] = s3_.h; P_##bl[3] = s3_.l;           \
    P_##bh[4] = s4_.h; P_##bl[4] = s4_.l; P_##bh[5] = s5_.h; P_##bl[5] = s5_.l;           \
    P_##bh[6] = s6_.h; P_##bl[6] = s6_.l; P_##bh[7] = s7_.h; P_##bl[7] = s7_.l; } while (0)
#define PMM(P_) do {                                                                    \
    acc = __builtin_amdgcn_mfma_f32_16x16x32_bf16(P_##ah, P_##bh, acc, 0, 0, 0);        \
    acc = __builtin_amdgcn_mfma_f32_16x16x32_bf16(P_##ah, P_##bl, acc, 0, 0, 0);        \
    acc = __builtin_amdgcn_mfma_f32_16x16x32_bf16(P_##al, P_##bh, acc, 0, 0, 0); } while (0)
#define PSTEP(P_, KN) do { PMM(P_); if ((KN) < 16) PLD(P_, KN); } while (0)

    PLD(A_, 0); PLD(B_, 1);
    PSTEP(A_, 2);  PSTEP(B_, 3);  PSTEP(A_, 4);  PSTEP(B_, 5);
    PSTEP(A_, 6);  PSTEP(B_, 7);  PSTEP(A_, 8);  PSTEP(B_, 9);
    PSTEP(A_, 10); PSTEP(B_, 11); PSTEP(A_, 12); PSTEP(B_, 13);
    PSTEP(A_, 14); PSTEP(B_, 15); PSTEP(A_, 16); PSTEP(B_, 17);
#undef PLD
#undef PMM
#undef PSTEP

    const int gcol = bx * 32 + wn * 16 + lr;
#pragma unroll
    for (int r = 0; r < 4; ++r) {
        const int row = by * 32 + wm * 16 + (lane >> 4) * 4 + r;
        const int b = row / Tn, t = row % Tn;
        const float a = acc[r];
        if (gcol < 1536) {
            const float val = a + bkkq[gcol];
            const int third = gcol >> 9, nh = gcol & 511, n = nh >> 6, hh = nh & 63;
            float* dst = (third == 0) ? k1 : (third == 1) ? k2 : qv;
            dst[((b * NH + n) * Tn + t) * HD + hh] = val;
        } else if (gcol < 2048) {
            const int c = gcol - 1536;
            float val = a + bv1[c];
            val = val / (1.f + __expf(-val));
            sv1[((b * NH + (c >> 6)) * Tn + t) * HD + (c & 63)] = val;
        } else {
            const int c = gcol - 2048;
            v2o[((b * NH + (c >> 6)) * Tn + t) * HD + (c & 63)] = a + bv2[c];
        }
    }
}

// ---------------- Kernel 2: exp tables + fused chunk partials ----------------
__global__ __launch_bounds__(256) void k_scoresP(
    const float* __restrict__ k1, const float* __restrict__ k2,
    const float* __restrict__ qv, const float* __restrict__ sv1,
    float* __restrict__ Ekk, float* __restrict__ Eqk,
    float* __restrict__ P, float* __restrict__ gP)
{
    const int bn = blockIdx.y;
    int bx = blockIdx.x;
    const int mat = (bx >= 36) ? 1 : 0;
    if (mat) bx -= 36;
    const int st = bx / 6, tt = bx % 6;
    const float* A  = ((mat == 0) ? k1 : qv) + bn * Tn * HD;
    const float* Bm = k2 + bn * Tn * HD;
    float* E = ((mat == 0) ? Ekk : Eqk) + bn * TT;

    __shared__ float As[32][65], Bs[32][65], Vs[32][65];
    __shared__ float Es[32][33];
    const int tid = threadIdx.x;
    for (int i = tid; i < 32 * 64; i += 256) {
        const int r = i >> 6, h = i & 63;
        As[r][h] = A[(st * 32 + r) * HD + h];
        Bs[r][h] = Bm[(tt * 32 + r) * HD + h];
        if (mat == 0) Vs[r][h] = sv1[bn * Tn * HD + (st * 32 + r) * HD + h];
    }
    __syncthreads();

    const int tx = tid & 15, ty = tid >> 4;
    const int r0 = ty * 2, c0 = tx * 2;
    float a00 = 0.f, a01 = 0.f, a10 = 0.f, a11 = 0.f;
#pragma unroll
    for (int h = 0; h < 64; ++h) {
        const float ar0 = As[r0][h], ar1 = As[r0 + 1][h];
        const float bc0 = Bs[c0][h], bc1 = Bs[c0 + 1][h];
        a00 = fmaf(ar0, bc0, a00); a01 = fmaf(ar0, bc1, a01);
        a10 = fmaf(ar1, bc0, a10); a11 = fmaf(ar1, bc1, a11);
    }
    constexpr float sc = 1.f / 64.f;
    const float e00 = __expf(a00 * sc), e01 = __expf(a01 * sc);
    const float e10 = __expf(a10 * sc), e11 = __expf(a11 * sc);
    const int gr = st * 32 + r0, gc = tt * 32 + c0;
    E[(gr)     * Tn + gc]     = e00;
    E[(gr)     * Tn + gc + 1] = e01;
    E[(gr + 1) * Tn + gc]     = e10;
    E[(gr + 1) * Tn + gc + 1] = e11;

    if (mat == 0) {
        Es[r0][c0] = e00; Es[r0][c0 + 1] = e01;
        Es[r0 + 1][c0] = e10; Es[r0 + 1][c0 + 1] = e11;
        __syncthreads();

        const int h   = tid >> 2;
        const int tp0 = (tid & 3) * 8;
        float p[8] = {0.f,0.f,0.f,0.f,0.f,0.f,0.f,0.f};
        for (int s = 0; s < 32; ++s) {
            const float a = Vs[s][h];
#pragma unroll
            for (int j = 0; j < 8; ++j) p[j] = fmaf(Es[s][tp0 + j], a, p[j]);
        }
        float* pd = P + ((bn * NCc + st) * HD + h) * Tn + tt * 32 + tp0;
        *reinterpret_cast<float4*>(&pd[0]) = make_float4(p[0], p[1], p[2], p[3]);
        *reinterpret_cast<float4*>(&pd[4]) = make_float4(p[4], p[5], p[6], p[7]);

        if (tid < 32) {
            float s = 0.f;
#pragma unroll
            for (int ss = 0; ss < 32; ++ss) s += Es[ss][tid];
            gP[(bn * NCc + st) * Tn + tt * 32 + tid] = s;
        }
    }
}

// ---------------- Kernel 3: attention from unscanned chunk partials ---------
__global__ __launch_bounds__(256) void k_attn2(
    const float* __restrict__ Ekk, const float* __restrict__ Eqk,
    const float* __restrict__ sv1, const float* __restrict__ v2,
    const float* __restrict__ P,   const float* __restrict__ gP,
    float* __restrict__ z)
{
    const int hq = blockIdx.x;
    const int qt = blockIdx.y;
    const int bn = blockIdx.z;
    const int b = bn >> 3, n = bn & 7;
    const int tid = threadIdx.x;
    const int tg  = tid & 15;
    const int hh  = tid >> 4;
    const int h   = hq * 16 + hh;
    const int t0  = tg * 12;
    const int q0  = qt * 12;
    const int cb  = q0 >> 5;

    const float* ekk = Ekk + bn * TT;
    const float* eqk = Eqk + bn * TT;
    const float* s1  = sv1 + bn * Tn * HD;
    const float* vv  = v2  + bn * Tn * HD;

    float G[12], g[12];
#pragma unroll
    for (int j = 0; j < 12; ++j) { G[j] = 0.f; g[j] = 0.f; }

    for (int c = 0; c < cb; ++c) {
        const float* pb = P  + ((bn * NCc + c) * HD + h) * Tn + t0;
        const float* gb = gP + (bn * NCc + c) * Tn + t0;
#pragma unroll
        for (int jj = 0; jj < 3; ++jj) {
            const float4 pv = *reinterpret_cast<const float4*>(&pb[4 * jj]);
            G[4*jj+0] += pv.x; G[4*jj+1] += pv.y; G[4*jj+2] += pv.z; G[4*jj+3] += pv.w;
            const float4 gv = *reinterpret_cast<const float4*>(&gb[4 * jj]);
            g[4*jj+0] += gv.x; g[4*jj+1] += gv.y; g[4*jj+2] += gv.z; g[4*jj+3] += gv.w;
        }
    }

    float vvr[12];
#pragma unroll
    for (int j = 0; j < 12; ++j) vvr[j] = vv[(t0 + j) * HD + h];

    for (int s = CSc * cb; s < q0; ++s) {
        const float a = s1[s * HD + h];
        const float* ek = ekk + s * Tn + t0;
#pragma unroll
        for (int jj = 0; jj < 3; ++jj) {
            const float4 ev = *reinterpret_cast<const float4*>(&ek[4 * jj]);
            G[4*jj+0] = fmaf(ev.x, a, G[4*jj+0]); g[4*jj+0] += ev.x;
            G[4*jj+1] = fmaf(ev.y, a, G[4*jj+1]); g[4*jj+1] += ev.y;
            G[4*jj+2] = fmaf(ev.z, a, G[4*jj+2]); g[4*jj+2] += ev.z;
            G[4*jj+3] = fmaf(ev.w, a, G[4*jj+3]); g[4*jj+3] += ev.w;
        }
    }

    for (int q = q0; q < q0 + 12; ++q) {
        {
            const float a = s1[q * HD + h];
            const float* ek = ekk + q * Tn + t0;
#pragma unroll
            for (int jj = 0; jj < 3; ++jj) {
                const float4 ev = *reinterpret_cast<const float4*>(&ek[4 * jj]);
                G[4*jj+0] = fmaf(ev.x, a, G[4*jj+0]); g[4*jj+0] += ev.x;
                G[4*jj+1] = fmaf(ev.y, a, G[4*jj+1]); g[4*jj+1] += ev.y;
                G[4*jj+2] = fmaf(ev.z, a, G[4*jj+2]); g[4*jj+2] += ev.z;
                G[4*jj+3] = fmaf(ev.w, a, G[4*jj+3]); g[4*jj+3] += ev.w;
            }
        }
        const float* eq = eqk + q * Tn + t0;
        float zp = 0.f, Zp = 0.f;
#pragma unroll
        for (int jj = 0; jj < 3; ++jj) {
            const float4 ev = *reinterpret_cast<const float4*>(&eq[4 * jj]);
            const float e0 = (t0 + 4*jj + 0 <= q) ? ev.x : 0.f;
            const float e1 = (t0 + 4*jj + 1 <= q) ? ev.y : 0.f;
            const float e2 = (t0 + 4*jj + 2 <= q) ? ev.z : 0.f;
            const float e3 = (t0 + 4*jj + 3 <= q) ? ev.w : 0.f;
            zp = fmaf(e0 * vvr[4*jj+0], G[4*jj+0], zp); Zp = fmaf(e0, g[4*jj+0], Zp);
            zp = fmaf(e1 * vvr[4*jj+1], G[4*jj+1], zp); Zp = fmaf(e1, g[4*jj+1], Zp);
            zp = fmaf(e2 * vvr[4*jj+2], G[4*jj+2], zp); Zp = fmaf(e2, g[4*jj+2], Zp);
            zp = fmaf(e3 * vvr[4*jj+3], G[4*jj+3], zp); Zp = fmaf(e3, g[4*jj+3], Zp);
        }
        zp += __shfl_xor(zp, 1); zp += __shfl_xor(zp, 2);
        zp += __shfl_xor(zp, 4); zp += __shfl_xor(zp, 8);
        Zp += __shfl_xor(Zp, 1); Zp += __shfl_xor(Zp, 2);
        Zp += __shfl_xor(Zp, 4); Zp += __shfl_xor(Zp, 8);
        if (tg == 0) z[((b * Tn + q) * NH + n) * HD + h] = zp / Zp;
    }
}

// ---------------- Kernel 4: MFMA output projection (fp32 in, in-reg split) --
// [384x512] @ [512x512]; 16x64 tile, 4 waves (16x16 each), 2-deep prefetch.
__global__ __launch_bounds__(256) void k_outm(
    const float* __restrict__ z, const float* __restrict__ Wout,
    const float* __restrict__ bout, float* __restrict__ out)
{
    const int bx = blockIdx.x, by = blockIdx.y;   // 8 col-tiles, 24 row-tiles
    const int tid = threadIdx.x;
    const int w = tid >> 6, lane = tid & 63;
    const int lr = lane & 15, lk = (lane >> 4) * 8;
    const int arow = by * 16 + lr;
    const int bcol = bx * 64 + w * 16 + lr;
    const float* zrow = z + arow * DM;

    f32x4 acc = {0.f,0.f,0.f,0.f};
    bf16x8 A_ah, A_al, A_bh, A_bl;
    bf16x8 B_ah, B_al, B_bh, B_bl;

#define OLD(P_, KS) do { const int ko_ = (KS) * 32 + lk;                                  \
    const float4 u0 = *reinterpret_cast<const float4*>(&zrow[ko_]);                       \
    const float4 u1 = *reinterpret_cast<const float4*>(&zrow[ko_ + 4]);                   \
    const float* wp_ = Wout + ko_ * DM + bcol;                                            \
    const float w0_ = wp_[0],      w1_ = wp_[DM],     w2_ = wp_[2 * DM];                  \
    const float w3_ = wp_[3 * DM], w4_ = wp_[4 * DM], w5_ = wp_[5 * DM];                  \
    const float w6_ = wp_[6 * DM], w7_ = wp_[7 * DM];                                     \
    bf16pair t0_ = split_bf16(u0.x), t1_ = split_bf16(u0.y);                              \
    bf16pair t2_ = split_bf16(u0.z), t3_ = split_bf16(u0.w);                              \
    bf16pair t4_ = split_bf16(u1.x), t5_ = split_bf16(u1.y);                              \
    bf16pair t6_ = split_bf16(u1.z), t7_ = split_bf16(u1.w);                              \
    P_##ah[0] = t0_.h; P_##al[0] = t0_.l; P_##ah[1] = t1_.h; P_##al[1] = t1_.l;           \
    P_##ah[2] = t2_.h; P_##al[2] = t2_.l; P_##ah[3] = t3_.h; P_##al[3] = t3_.l;           \
    P_##ah[4] = t4_.h; P_##al[4] = t4_.l; P_##ah[5] = t5_.h; P_##al[5] = t5_.l;           \
    P_##ah[6] = t6_.h; P_##al[6] = t6_.l; P_##ah[7] = t7_.h; P_##al[7] = t7_.l;           \
    bf16pair s0_ = split_bf16(w0_), s1_ = split_bf16(w1_);                                \
    bf16pair s2_ = split_bf16(w2_), s3_ = split_bf16(w3_);                                \
    bf16pair s4_ = split_bf16(w4_), s5_ = split_bf16(w5_);                                \
    bf16pair s6_ = split_bf16(w6_), s7_ = split_bf16(w7_);                                \
    P_##bh[0] = s0_.h; P_##bl[0] = s0_.l; P_##bh[1] = s1_.h; P_##bl[1] = s1_.l;           \
    P_##bh[2] = s2_.h; P_##bl[2] = s2_.l; P_##bh[3] = s3_.h; P_##bl[3] = s3_.l;           \
    P_##bh[4] = s4_.h; P_##bl[4] = s4_.l; P_##bh[5] = s5_.h; P_##bl[5] = s5_.l;           \
    P_##bh[6] = s6_.h; P_##bl[6] = s6_.l; P_##bh[7] = s7_.h; P_##bl[7] = s7_.l; } while (0)
#define OMM(P_) do {                                                                   \
    acc = __builtin_amdgcn_mfma_f32_16x16x32_bf16(P_##ah, P_##bh, acc, 0, 0, 0);       \
    acc = __builtin_amdgcn_mfma_f32_16x16x32_bf16(P_##ah, P_##bl, acc, 0, 0, 0);       \
    acc = __builtin_amdgcn_mfma_f32_16x16x32_bf16(P_##al, P_##bh, acc, 0, 0, 0); } while (0)
#define OSTEP(P_, KN) do { OMM(P_); if ((KN) < 16) OLD(P_, KN); } while (0)

    OLD(A_, 0); OLD(B_, 1);
    OSTEP(A_, 2);  OSTEP(B_, 3);  OSTEP(A_, 4);  OSTEP(B_, 5);
    OSTEP(A_, 6);  OSTEP(B_, 7);  OSTEP(A_, 8);  OSTEP(B_, 9);
    OSTEP(A_, 10); OSTEP(B_, 11); OSTEP(A_, 12); OSTEP(B_, 13);
    OSTEP(A_, 14); OSTEP(B_, 15); OSTEP(A_, 16); OSTEP(B_, 17);
#undef OLD
#undef OMM
#undef OSTEP

#pragma unroll
    for (int r = 0; r < 4; ++r) {
        const int row = by * 16 + (lane >> 4) * 4 + r;
        out[row * DM + bcol] = acc[r] + bout[bcol];
    }
}

extern "C" void kernel_launch(void* const* d_in, const int* in_sizes, int n_in,
                              void* d_out, int out_size, void* d_ws, size_t ws_size,
                              hipStream_t stream) {
    const float* x    = (const float*)d_in[0];
    const float* Wkkq = (const float*)d_in[1];
    const float* bkkq = (const float*)d_in[2];
    const float* Wv1  = (const float*)d_in[3];
    const float* bv1  = (const float*)d_in[4];
    const float* Wv2  = (const float*)d_in[5];
    const float* bv2  = (const float*)d_in[6];
    const float* Wout = (const float*)d_in[7];
    const float* bout = (const float*)d_in[8];
    float* out = (float*)d_out;

    float* ws  = (float*)d_ws;
    float* k1  = ws;
    float* k2  = k1  + 196608;
    float* qv  = k2  + 196608;
    float* sv1 = qv  + 196608;
    float* v2  = sv1 + 196608;
    float* z   = v2  + 196608;
    float* Ekk = z   + 196608;
    float* Eqk = Ekk + 589824;
    float* P   = Eqk + 589824;           // 16*6*64*192
    float* gP  = P   + 1179648;          // 16*6*192

    k_projm  <<<dim3(80, 12),    256, 0, stream>>>(x, Wkkq, Wv1, Wv2,
                                                   bkkq, bv1, bv2,
                                                   k1, k2, qv, sv1, v2);
    k_scoresP<<<dim3(72, 16),    256, 0, stream>>>(k1, k2, qv, sv1, Ekk, Eqk, P, gP);
    k_attn2  <<<dim3(4, 16, 16), 256, 0, stream>>>(Ekk, Eqk, sv1, v2, P, gP, z);
    k_outm   <<<dim3(8, 24),     256, 0, stream>>>(z, Wout, bout, out);
}